// Round 3
// baseline (176.121 us; speedup 1.0000x reference)
//
#include <hip/hip_runtime.h>
#include <hip/hip_bf16.h>

#define B_    4
#define N_    16384
#define D_    128
#define P_    100
#define BN_   65536      // B_*N_
#define PBN_  6553600    // P_*BN_
#define PPAD  112        // P padded to 7*16 MFMA p-tiles (k_proj)
#define KPAD  128        // P padded to 128 for k_comb's K dimension
#define NBIN  4096

typedef __attribute__((ext_vector_type(8))) short short8;   // 8 bf16 = 4 VGPR
typedef __attribute__((ext_vector_type(4))) float floatx4;  // MFMA C/D

// bf16 <-> f32 via raw bits (RNE; inputs are finite)
__device__ __forceinline__ unsigned short f2b(float f) {
    unsigned u = __float_as_uint(f);
    return (unsigned short)((u + 0x7FFFu + ((u >> 16) & 1u)) >> 16);
}
__device__ __forceinline__ float b2f(unsigned short h) {
    return __uint_as_float(((unsigned)h) << 16);
}

// ---------------------------------------------------------------------------
// Kernel 1: theta normalization -> thb[p][d] (k_proj A-operand, rows >=100
// zero) and thbT[d][p] (k_comb B-operand, cols >=100 zero; NaN-safe K-pad).
// ---------------------------------------------------------------------------
__global__ void k_norm(const float* __restrict__ th,
                       unsigned short* __restrict__ thb,
                       unsigned short* __restrict__ thbT) {
    int p = blockIdx.x;       // 0..127
    int d = threadIdx.x;      // 0..127
    float v = 0.f;
    if (p < P_) v = th[p * D_ + d];
    float s = v * v;
    #pragma unroll
    for (int o = 32; o > 0; o >>= 1) s += __shfl_down(s, o, 64);
    __shared__ float red[2];
    if ((d & 63) == 0) red[d >> 6] = s;
    __syncthreads();
    float norm = fmaxf(sqrtf(red[0] + red[1]), 1e-12f);
    unsigned short r = f2b(v / norm);       // p>=100 -> 0/1e-12 = +0
    if (p < PPAD) thb[p * D_ + d] = r;
    thbT[d * KPAD + p] = r;
}

// ---------------------------------------------------------------------------
// Kernel 2: projections via bf16 MFMA 16x16x32.
// R2 restructure: x/y LDS staging ELIMINATED.  The B-fragment a lane needs is
// 8 consecutive dims of one row -> load 2x float4 straight from global
// (wave = 16 rows x 64B segments, coalesced), convert f32->bf16 in-register.
// All 16 float4 loads issue up-front (deep MLP, reg staging); LDS keeps only
// theta (shared across waves) + output-coalescing buffers.  Barriers 3 -> 2;
// 68 KB/block LDS round-trip removed; LDS 62.7 KB -> 2 blocks/CU.
// ---------------------------------------------------------------------------
__global__ __launch_bounds__(256, 2) void k_proj(
    const float* __restrict__ x, const float* __restrict__ y,
    const unsigned short* __restrict__ thb,
    unsigned short* __restrict__ xp, unsigned short* __restrict__ yp) {
    __shared__ unsigned short th_s[15232];    // [112][136] 30,464 B
    __shared__ unsigned short bufx[8064];     // [112][72]  16,128 B
    __shared__ unsigned short bufy[8064];     // [112][72]  16,128 B
    const int tid  = threadIdx.x;
    const int w    = tid >> 6;                // wave 0..3 -> rows w*16..+15
    const int lane = tid & 63;
    const int n    = lane & 15;
    const int quad = lane >> 4;
    const int row0 = blockIdx.x * 64;

    for (int g = tid; g < 1792; g += 256) {   // theta 112x128 bf16 -> LDS
        int r = g >> 4, c = (g & 15) << 3;
        *(uint4*)(th_s + r * 136 + c) = *(const uint4*)(thb + r * D_ + c);
    }

    // direct global loads of this lane's B-fragments (16 float4, issued early)
    const float* xr = x + (size_t)(row0 + w * 16 + n) * D_ + quad * 8;
    const float* yr = y + (size_t)(row0 + w * 16 + n) * D_ + quad * 8;
    float4 lx[8], ly[8];
    #pragma unroll
    for (int ks = 0; ks < 4; ++ks) {
        lx[2*ks]   = *(const float4*)(xr + ks * 32);
        lx[2*ks+1] = *(const float4*)(xr + ks * 32 + 4);
        ly[2*ks]   = *(const float4*)(yr + ks * 32);
        ly[2*ks+1] = *(const float4*)(yr + ks * 32 + 4);
    }
    short8 bx[4], by[4];
    #pragma unroll
    for (int ks = 0; ks < 4; ++ks) {
        short8 tx, ty;
        tx[0] = (short)f2b(lx[2*ks].x);   ty[0] = (short)f2b(ly[2*ks].x);
        tx[1] = (short)f2b(lx[2*ks].y);   ty[1] = (short)f2b(ly[2*ks].y);
        tx[2] = (short)f2b(lx[2*ks].z);   ty[2] = (short)f2b(ly[2*ks].z);
        tx[3] = (short)f2b(lx[2*ks].w);   ty[3] = (short)f2b(ly[2*ks].w);
        tx[4] = (short)f2b(lx[2*ks+1].x); ty[4] = (short)f2b(ly[2*ks+1].x);
        tx[5] = (short)f2b(lx[2*ks+1].y); ty[5] = (short)f2b(ly[2*ks+1].y);
        tx[6] = (short)f2b(lx[2*ks+1].z); ty[6] = (short)f2b(ly[2*ks+1].z);
        tx[7] = (short)f2b(lx[2*ks+1].w); ty[7] = (short)f2b(ly[2*ks+1].w);
        bx[ks] = tx; by[ks] = ty;
    }
    __syncthreads();                          // theta staged

    #pragma unroll
    for (int pt = 0; pt < 7; ++pt) {
        floatx4 accx = {0.f, 0.f, 0.f, 0.f};
        floatx4 accy = {0.f, 0.f, 0.f, 0.f};
        #pragma unroll
        for (int ks = 0; ks < 4; ++ks) {
            short8 a = *(const short8*)(th_s + (pt * 16 + n) * 136 + ks * 32 + quad * 8);
            accx = __builtin_amdgcn_mfma_f32_16x16x32_bf16(a, bx[ks], accx, 0, 0, 0);
            accy = __builtin_amdgcn_mfma_f32_16x16x32_bf16(a, by[ks], accy, 0, 0, 0);
        }
        #pragma unroll
        for (int reg = 0; reg < 4; ++reg) {
            int p = pt * 16 + quad * 4 + reg;
            bufx[p * 72 + w * 16 + n] = f2b(accx[reg]);
            bufy[p * 72 + w * 16 + n] = f2b(accy[reg]);
        }
    }
    __syncthreads();

    for (int g = tid; g < 896; g += 256) {    // coalesced 128B-segment writes
        int p = g >> 3, c = (g & 7) << 3;
        *(uint4*)(xp + (size_t)p * BN_ + row0 + c) = *(const uint4*)(bufx + p * 72 + c);
        *(uint4*)(yp + (size_t)p * BN_ + row0 + c) = *(const uint4*)(bufy + p * 72 + c);
    }
}

// ---------------------------------------------------------------------------
// Kernel 3: fused counting sort + rank + diff.  Packed histogram: y counts in
// low 16 (+1), x counts in high 16 (+0x10000); max count 16384 < 2^16 so the
// packed exclusive scan is field-independent (total 0x4000_4000, no carry).
//
// R2 fix: 512 threads x 32 elems (was 1024 x 16).  At 1024 thr the <=128
// VGPR cap forces 1 block/CU -> 400 blocks = 2 strict scheduling rounds with
// all barrier/scan/load latency exposed.  512 thr keeps live state ~90 VGPR
// under launch_bounds(512,4) (cap 128, no spill), fits 2 blocks/CU -> whole
// grid co-resident, blocks mutually hide each other's barriers.  Element
// ownership re-mapped so every load/store instruction is wave-contiguous
// (64 lanes x 16 B = 1 KB/instr).
// ---------------------------------------------------------------------------
__device__ __forceinline__ int binof(float v) {
    int k = (int)((v + 8.0f) * 256.0f);
    return k < 0 ? 0 : (k > NBIN - 1 ? NBIN - 1 : k);
}

__device__ __forceinline__ void scan8(unsigned* hist, volatile unsigned* wsum, int t) {
    unsigned v[8], run = 0;
    #pragma unroll
    for (int i = 0; i < 8; ++i) { unsigned h = hist[t * 8 + i]; v[i] = run; run += h; }
    const int lane = t & 63, w = t >> 6;      // w 0..7
    unsigned inc = run;
    #pragma unroll
    for (int off = 1; off < 64; off <<= 1) {
        unsigned nbr = __shfl_up(inc, off, 64);
        if (lane >= off) inc += nbr;
    }
    if (lane == 63) wsum[w] = inc;
    __syncthreads();
    if (t == 0) {
        unsigned r2 = 0;
        #pragma unroll
        for (int i = 0; i < 8; ++i) { unsigned h = wsum[i]; wsum[i] = r2; r2 += h; }
    }
    __syncthreads();
    unsigned base = wsum[w] + (inc - run);
    #pragma unroll
    for (int i = 0; i < 8; ++i) hist[t * 8 + i] = base + v[i];
}

__global__ __launch_bounds__(512, 4) void k_sortdiff(
    const unsigned short* __restrict__ xp, const unsigned short* __restrict__ yp,
    unsigned short* __restrict__ diff) {
    __shared__ unsigned hist[NBIN];           // 16 KB (packed y|x)
    __shared__ unsigned short ysort[N_];      // 32 KB
    __shared__ unsigned wsum[8];
    const int t = threadIdx.x;
    const unsigned* ypd = (const unsigned*)(yp + (size_t)blockIdx.x * N_);
    const unsigned* xpd = (const unsigned*)(xp + (size_t)blockIdx.x * N_);
    unsigned*       dfd = (unsigned*)(diff + (size_t)blockIdx.x * N_);

    // 32 elems/thread; per-instruction wave-contiguous uint4 loads
    unsigned yw[16], xw[16];
    #pragma unroll
    for (int i = 0; i < 4; ++i) {
        uint4 a = *(const uint4*)(ypd + i * 2048 + t * 4);
        yw[4*i] = a.x; yw[4*i+1] = a.y; yw[4*i+2] = a.z; yw[4*i+3] = a.w;
        uint4 c = *(const uint4*)(xpd + i * 2048 + t * 4);
        xw[4*i] = c.x; xw[4*i+1] = c.y; xw[4*i+2] = c.z; xw[4*i+3] = c.w;
    }

    #pragma unroll
    for (int i = 0; i < 8; ++i) hist[t + i * 512] = 0;
    __syncthreads();

    // ---- single packed count pass (returning: own field IS intra-bin idx) ----
    unsigned jy[16], jx[16];
    #pragma unroll
    for (int k = 0; k < 16; ++k) {
        unsigned j0 = atomicAdd(&hist[binof(b2f((unsigned short)(yw[k] & 0xffff)))], 1u);
        unsigned j1 = atomicAdd(&hist[binof(b2f((unsigned short)(yw[k] >> 16)))], 1u);
        jy[k] = (j0 & 0xffffu) | (j1 << 16);
        unsigned i0 = atomicAdd(&hist[binof(b2f((unsigned short)(xw[k] & 0xffff)))], 0x10000u);
        unsigned i1 = atomicAdd(&hist[binof(b2f((unsigned short)(xw[k] >> 16)))], 0x10000u);
        jx[k] = (i0 >> 16) | (i1 & 0xffff0000u);
    }
    __syncthreads();
    scan8(hist, wsum, t);                     // packed exclusive prefix, both fields
    __syncthreads();

    // scatter y into LDS (low field) and fold x rank into jx (high field)
    #pragma unroll
    for (int k = 0; k < 16; ++k) {
        unsigned short e0 = (unsigned short)(yw[k] & 0xffff);
        unsigned short e1 = (unsigned short)(yw[k] >> 16);
        ysort[(hist[binof(b2f(e0))] & 0xffffu) + (jy[k] & 0xffffu)] = e0;
        ysort[(hist[binof(b2f(e1))] & 0xffffu) + (jy[k] >> 16)]     = e1;
        unsigned r0 = (hist[binof(b2f((unsigned short)(xw[k] & 0xffff)))] >> 16) + (jx[k] & 0xffffu);
        unsigned r1 = (hist[binof(b2f((unsigned short)(xw[k] >> 16)))] >> 16) + (jx[k] >> 16);
        jx[k] = r0 | (r1 << 16);
    }
    __syncthreads();

    // gather transported y, write diff (wave-contiguous uint4 stores)
    #pragma unroll
    for (int i = 0; i < 4; ++i) {
        unsigned o[4];
        #pragma unroll
        for (int q = 0; q < 4; ++q) {
            int k = 4*i + q;
            float x0 = b2f((unsigned short)(xw[k] & 0xffff));
            float x1 = b2f((unsigned short)(xw[k] >> 16));
            unsigned short d0 = f2b(b2f(ysort[jx[k] & 0xffffu]) - x0);
            unsigned short d1 = f2b(b2f(ysort[jx[k] >> 16]) - x1);
            o[q] = (unsigned)d0 | ((unsigned)d1 << 16);
        }
        *(uint4*)(dfd + i * 2048 + t * 4) = make_uint4(o[0], o[1], o[2], o[3]);
    }
}

// ---------------------------------------------------------------------------
// Kernel 4: combine via bf16 MFMA, transpose fused into the LDS stage.
// Per block: stage diff[p][row0..row0+64] for p=0..99 (100 coalesced 128 B
// segments) pair-packed into Lp[k2][row] (dword = {k even lo16, k odd hi16});
// k2 rows 50..63 zeroed = NaN-safe K-pad.  A-frags: ds_read_b32 at (k2)*68+r
// dwords — 2-way bank aliasing = free (m136).  B = thbT in LDS [128][136].
// C[m=row][n=d]; out = x + C/P.  LDS 52,224 B -> 3 blocks/CU, 12 waves/CU.
// ---------------------------------------------------------------------------
__global__ __launch_bounds__(256) void k_comb(
    const float* __restrict__ x, const unsigned short* __restrict__ diff,
    const unsigned short* __restrict__ thbT, float* __restrict__ out) {
    __shared__ unsigned short ths[128 * 136]; // 34,816 B
    __shared__ unsigned Lp[64 * 68];          // 17,408 B  [k2][row] pair-packed
    const int tid  = threadIdx.x;
    const int w    = tid >> 6;                // wave -> rows w*16..+15
    const int lane = tid & 63;
    const int n16  = lane & 15;
    const int quad = lane >> 4;
    const int row0 = blockIdx.x * 64;

    for (int g = tid; g < 2048; g += 256) {   // thbT 128x128 bf16 -> LDS
        int r = g >> 4, c = (g & 15) << 3;
        *(uint4*)(ths + r * 136 + c) = *(const uint4*)(thbT + r * KPAD + c);
    }
    for (int g = tid; g < 952; g += 256) Lp[50 * 68 + g] = 0;   // k2=50..63 pad
    for (int g = tid; g < 400; g += 256) {    // 50 p-pairs x 8 row-groups
        int p2 = g >> 3, rg = (g & 7) << 3;
        uint4 a = *(const uint4*)(diff + (size_t)(2 * p2) * BN_ + row0 + rg);
        uint4 b = *(const uint4*)(diff + (size_t)(2 * p2 + 1) * BN_ + row0 + rg);
        unsigned* dst = Lp + p2 * 68 + rg;
        dst[0] = (a.x & 0xffffu) | (b.x << 16);
        dst[1] = (a.x >> 16)     | (b.x & 0xffff0000u);
        dst[2] = (a.y & 0xffffu) | (b.y << 16);
        dst[3] = (a.y >> 16)     | (b.y & 0xffff0000u);
        dst[4] = (a.z & 0xffffu) | (b.z << 16);
        dst[5] = (a.z >> 16)     | (b.z & 0xffff0000u);
        dst[6] = (a.w & 0xffffu) | (b.w << 16);
        dst[7] = (a.w >> 16)     | (b.w & 0xffff0000u);
    }
    __syncthreads();

    // A-frags: lane row r = w*16+n16, k = ks*32 + quad*8 + 0..7
    const int r = w * 16 + n16;
    short8 af[4];
    #pragma unroll
    for (int ks = 0; ks < 4; ++ks) {
        union { unsigned u[4]; short8 v; } tu;
        #pragma unroll
        for (int m = 0; m < 4; ++m)
            tu.u[m] = Lp[(ks * 16 + quad * 4 + m) * 68 + r];
        af[ks] = tu.v;
    }

    floatx4 acc[8];
    #pragma unroll
    for (int nt = 0; nt < 8; ++nt) {
        acc[nt] = (floatx4){0.f, 0.f, 0.f, 0.f};
        #pragma unroll
        for (int ks = 0; ks < 4; ++ks) {
            short8 b = *(const short8*)(ths + (nt * 16 + n16) * 136 + ks * 32 + quad * 8);
            acc[nt] = __builtin_amdgcn_mfma_f32_16x16x32_bf16(af[ks], b, acc[nt], 0, 0, 0);
        }
    }

    const float invP = 1.0f / (float)P_;
    const size_t rbase = (size_t)(row0 + w * 16 + quad * 4) * D_ + n16;
    #pragma unroll
    for (int nt = 0; nt < 8; ++nt)
        #pragma unroll
        for (int reg = 0; reg < 4; ++reg) {
            size_t o = rbase + (size_t)reg * D_ + nt * 16;
            out[o] = fmaf(acc[nt][reg], invP, x[o]);
        }
}

// ---------------------------------------------------------------------------
// Workspace (bytes): thb[0, 32KB) thbT[32KB, 64KB) xp[64KB, +13.1MB)
// yp(+13.1MB) => ~26.3 MB. diff overwrites xp in place.
// ---------------------------------------------------------------------------
extern "C" void kernel_launch(void* const* d_in, const int* in_sizes, int n_in,
                              void* d_out, int out_size, void* d_ws, size_t ws_size,
                              hipStream_t stream) {
    const float* x  = (const float*)d_in[0];
    const float* y  = (const float*)d_in[1];
    const float* th = (const float*)d_in[2];
    float* out = (float*)d_out;
    char*  wsb = (char*)d_ws;

    unsigned short* thb  = (unsigned short*)wsb;
    unsigned short* thbT = (unsigned short*)(wsb + 32768);
    unsigned short* xpb  = (unsigned short*)(wsb + 65536);
    unsigned short* ypb  = xpb + PBN_;

    k_norm<<<128, 128, 0, stream>>>(th, thb, thbT);
    k_proj<<<BN_ / 64, 256, 0, stream>>>(x, y, thb, xpb, ypb);
    k_sortdiff<<<P_ * B_, 512, 0, stream>>>(xpb, ypb, xpb);
    k_comb<<<BN_ / 64, 256, 0, stream>>>(x, xpb, thbT, out);
}

// Round 4
// 148.947 us; speedup vs baseline: 1.1824x; 1.1824x over previous
//
#include <hip/hip_runtime.h>
#include <hip/hip_bf16.h>

#define B_    4
#define N_    16384
#define D_    128
#define P_    100
#define BN_   65536      // B_*N_
#define PBN_  6553600    // P_*BN_
#define PPAD  112        // P padded to 7*16 MFMA p-tiles (k_proj)
#define KPAD  128        // P padded to 128 for k_comb's K dimension
#define NBIN  4096

typedef __attribute__((ext_vector_type(8))) short short8;   // 8 bf16 = 4 VGPR
typedef __attribute__((ext_vector_type(4))) float floatx4;  // MFMA C/D

// bf16 <-> f32 via raw bits (RNE; inputs are finite)
__device__ __forceinline__ unsigned short f2b(float f) {
    unsigned u = __float_as_uint(f);
    return (unsigned short)((u + 0x7FFFu + ((u >> 16) & 1u)) >> 16);
}
__device__ __forceinline__ float b2f(unsigned short h) {
    return __uint_as_float(((unsigned)h) << 16);
}

// ---------------------------------------------------------------------------
// Kernel 1: theta normalization -> thb[p][d] (k_proj A-operand, rows >=100
// zero) and thbT[d][p] (k_comb B-operand, cols >=100 zero; NaN-safe K-pad).
// ---------------------------------------------------------------------------
__global__ void k_norm(const float* __restrict__ th,
                       unsigned short* __restrict__ thb,
                       unsigned short* __restrict__ thbT) {
    int p = blockIdx.x;       // 0..127
    int d = threadIdx.x;      // 0..127
    float v = 0.f;
    if (p < P_) v = th[p * D_ + d];
    float s = v * v;
    #pragma unroll
    for (int o = 32; o > 0; o >>= 1) s += __shfl_down(s, o, 64);
    __shared__ float red[2];
    if ((d & 63) == 0) red[d >> 6] = s;
    __syncthreads();
    float norm = fmaxf(sqrtf(red[0] + red[1]), 1e-12f);
    unsigned short r = f2b(v / norm);       // p>=100 -> 0/1e-12 = +0
    if (p < PPAD) thb[p * D_ + d] = r;
    thbT[d * KPAD + p] = r;
}

// ---------------------------------------------------------------------------
// Kernel 2: projections via bf16 MFMA 16x16x32.  (R3 version — validated:
// x/y staged via registers, direct coalesced float4 global loads, LDS only
// for theta + output-coalescing buffers.  Barriers 2; 2 blocks/CU.)
// ---------------------------------------------------------------------------
__global__ __launch_bounds__(256, 2) void k_proj(
    const float* __restrict__ x, const float* __restrict__ y,
    const unsigned short* __restrict__ thb,
    unsigned short* __restrict__ xp, unsigned short* __restrict__ yp) {
    __shared__ unsigned short th_s[15232];    // [112][136] 30,464 B
    __shared__ unsigned short bufx[8064];     // [112][72]  16,128 B
    __shared__ unsigned short bufy[8064];     // [112][72]  16,128 B
    const int tid  = threadIdx.x;
    const int w    = tid >> 6;                // wave 0..3 -> rows w*16..+15
    const int lane = tid & 63;
    const int n    = lane & 15;
    const int quad = lane >> 4;
    const int row0 = blockIdx.x * 64;

    for (int g = tid; g < 1792; g += 256) {   // theta 112x128 bf16 -> LDS
        int r = g >> 4, c = (g & 15) << 3;
        *(uint4*)(th_s + r * 136 + c) = *(const uint4*)(thb + r * D_ + c);
    }

    // direct global loads of this lane's B-fragments (16 float4, issued early)
    const float* xr = x + (size_t)(row0 + w * 16 + n) * D_ + quad * 8;
    const float* yr = y + (size_t)(row0 + w * 16 + n) * D_ + quad * 8;
    float4 lx[8], ly[8];
    #pragma unroll
    for (int ks = 0; ks < 4; ++ks) {
        lx[2*ks]   = *(const float4*)(xr + ks * 32);
        lx[2*ks+1] = *(const float4*)(xr + ks * 32 + 4);
        ly[2*ks]   = *(const float4*)(yr + ks * 32);
        ly[2*ks+1] = *(const float4*)(yr + ks * 32 + 4);
    }
    short8 bx[4], by[4];
    #pragma unroll
    for (int ks = 0; ks < 4; ++ks) {
        short8 tx, ty;
        tx[0] = (short)f2b(lx[2*ks].x);   ty[0] = (short)f2b(ly[2*ks].x);
        tx[1] = (short)f2b(lx[2*ks].y);   ty[1] = (short)f2b(ly[2*ks].y);
        tx[2] = (short)f2b(lx[2*ks].z);   ty[2] = (short)f2b(ly[2*ks].z);
        tx[3] = (short)f2b(lx[2*ks].w);   ty[3] = (short)f2b(ly[2*ks].w);
        tx[4] = (short)f2b(lx[2*ks+1].x); ty[4] = (short)f2b(ly[2*ks+1].x);
        tx[5] = (short)f2b(lx[2*ks+1].y); ty[5] = (short)f2b(ly[2*ks+1].y);
        tx[6] = (short)f2b(lx[2*ks+1].z); ty[6] = (short)f2b(ly[2*ks+1].z);
        tx[7] = (short)f2b(lx[2*ks+1].w); ty[7] = (short)f2b(ly[2*ks+1].w);
        bx[ks] = tx; by[ks] = ty;
    }
    __syncthreads();                          // theta staged

    #pragma unroll
    for (int pt = 0; pt < 7; ++pt) {
        floatx4 accx = {0.f, 0.f, 0.f, 0.f};
        floatx4 accy = {0.f, 0.f, 0.f, 0.f};
        #pragma unroll
        for (int ks = 0; ks < 4; ++ks) {
            short8 a = *(const short8*)(th_s + (pt * 16 + n) * 136 + ks * 32 + quad * 8);
            accx = __builtin_amdgcn_mfma_f32_16x16x32_bf16(a, bx[ks], accx, 0, 0, 0);
            accy = __builtin_amdgcn_mfma_f32_16x16x32_bf16(a, by[ks], accy, 0, 0, 0);
        }
        #pragma unroll
        for (int reg = 0; reg < 4; ++reg) {
            int p = pt * 16 + quad * 4 + reg;
            bufx[p * 72 + w * 16 + n] = f2b(accx[reg]);
            bufy[p * 72 + w * 16 + n] = f2b(accy[reg]);
        }
    }
    __syncthreads();

    for (int g = tid; g < 896; g += 256) {    // coalesced 128B-segment writes
        int p = g >> 3, c = (g & 7) << 3;
        *(uint4*)(xp + (size_t)p * BN_ + row0 + c) = *(const uint4*)(bufx + p * 72 + c);
        *(uint4*)(yp + (size_t)p * BN_ + row0 + c) = *(const uint4*)(bufy + p * 72 + c);
    }
}

// ---------------------------------------------------------------------------
// Kernel 3: fused counting sort + rank + diff.  Packed histogram: y counts in
// low 16 (+1), x counts in high 16 (+0x10000); max count 16384 < 2^16 so the
// packed exclusive scan is field-independent (total 0x4000_4000, no carry).
//
// R3 post-mortem: __launch_bounds__(512,4) resolved to an effective 64-VGPR
// cap (rocprof VGPR_Count=64) while 32 elems/thread needs 64+ words of live
// state -> scratch spill again (WRITE 76.8 MB vs 13.4 ideal, 53.7 us).
// REVERT to the proven R2 shape: 1024 thr x 16 elems, launch_bounds(1024,4)
// (empirically ~100 VGPR, zero spill, ~23 us), keeping only the register-
// neutral improvement: wave-contiguous uint4 mapping (lane-adjacent 16 B =>
// 1 KB/instruction per wave).
// ---------------------------------------------------------------------------
__device__ __forceinline__ int binof(float v) {
    int k = (int)((v + 8.0f) * 256.0f);
    return k < 0 ? 0 : (k > NBIN - 1 ? NBIN - 1 : k);
}

__device__ __forceinline__ void scan4(unsigned* hist, volatile unsigned* wsum, int t) {
    unsigned v[4], run = 0;
    #pragma unroll
    for (int i = 0; i < 4; ++i) { unsigned h = hist[t * 4 + i]; v[i] = run; run += h; }
    const int lane = t & 63, w = t >> 6;
    unsigned inc = run;
    #pragma unroll
    for (int off = 1; off < 64; off <<= 1) {
        unsigned nbr = __shfl_up(inc, off, 64);
        if (lane >= off) inc += nbr;
    }
    if (lane == 63) wsum[w] = inc;
    __syncthreads();
    if (t == 0) {
        unsigned r2 = 0;
        #pragma unroll
        for (int i = 0; i < 16; ++i) { unsigned h = wsum[i]; wsum[i] = r2; r2 += h; }
    }
    __syncthreads();
    unsigned base = wsum[w] + (inc - run);
    #pragma unroll
    for (int i = 0; i < 4; ++i) hist[t * 4 + i] = base + v[i];
}

__global__ __launch_bounds__(1024, 4) void k_sortdiff(
    const unsigned short* __restrict__ xp, const unsigned short* __restrict__ yp,
    unsigned short* __restrict__ diff) {
    __shared__ unsigned hist[NBIN];           // 16 KB (packed y|x)
    __shared__ unsigned short ysort[N_];      // 32 KB
    __shared__ unsigned wsum[16];
    const int t = threadIdx.x;
    const unsigned* ypd = (const unsigned*)(yp + (size_t)blockIdx.x * N_);
    const unsigned* xpd = (const unsigned*)(xp + (size_t)blockIdx.x * N_);
    unsigned*       dfd = (unsigned*)(diff + (size_t)blockIdx.x * N_);

    // 16 elems/thread; wave-contiguous uint4 loads (lane-adjacent 16 B)
    unsigned yw[8], xw[8];
    #pragma unroll
    for (int i = 0; i < 2; ++i) {
        uint4 a = *(const uint4*)(ypd + i * 4096 + t * 4);
        yw[4*i] = a.x; yw[4*i+1] = a.y; yw[4*i+2] = a.z; yw[4*i+3] = a.w;
        uint4 c = *(const uint4*)(xpd + i * 4096 + t * 4);
        xw[4*i] = c.x; xw[4*i+1] = c.y; xw[4*i+2] = c.z; xw[4*i+3] = c.w;
    }

    #pragma unroll
    for (int i = 0; i < 4; ++i) hist[t + i * 1024] = 0;
    __syncthreads();

    // ---- single packed count pass (returning: own field IS intra-bin idx) ----
    unsigned jy[8], jx[8];
    #pragma unroll
    for (int k = 0; k < 8; ++k) {
        unsigned j0 = atomicAdd(&hist[binof(b2f((unsigned short)(yw[k] & 0xffff)))], 1u);
        unsigned j1 = atomicAdd(&hist[binof(b2f((unsigned short)(yw[k] >> 16)))], 1u);
        jy[k] = (j0 & 0xffffu) | (j1 << 16);
        unsigned i0 = atomicAdd(&hist[binof(b2f((unsigned short)(xw[k] & 0xffff)))], 0x10000u);
        unsigned i1 = atomicAdd(&hist[binof(b2f((unsigned short)(xw[k] >> 16)))], 0x10000u);
        jx[k] = (i0 >> 16) | (i1 & 0xffff0000u);
    }
    __syncthreads();
    scan4(hist, wsum, t);                     // packed exclusive prefix, both fields
    __syncthreads();

    // scatter y into LDS (low field) and fold x rank into jx (high field)
    #pragma unroll
    for (int k = 0; k < 8; ++k) {
        unsigned short e0 = (unsigned short)(yw[k] & 0xffff);
        unsigned short e1 = (unsigned short)(yw[k] >> 16);
        ysort[(hist[binof(b2f(e0))] & 0xffffu) + (jy[k] & 0xffffu)] = e0;
        ysort[(hist[binof(b2f(e1))] & 0xffffu) + (jy[k] >> 16)]     = e1;
        unsigned r0 = (hist[binof(b2f((unsigned short)(xw[k] & 0xffff)))] >> 16) + (jx[k] & 0xffffu);
        unsigned r1 = (hist[binof(b2f((unsigned short)(xw[k] >> 16)))] >> 16) + (jx[k] >> 16);
        jx[k] = r0 | (r1 << 16);
    }
    __syncthreads();

    // gather transported y, write diff (wave-contiguous uint4 stores)
    #pragma unroll
    for (int i = 0; i < 2; ++i) {
        unsigned o[4];
        #pragma unroll
        for (int q = 0; q < 4; ++q) {
            int k = 4*i + q;
            float x0 = b2f((unsigned short)(xw[k] & 0xffff));
            float x1 = b2f((unsigned short)(xw[k] >> 16));
            unsigned short d0 = f2b(b2f(ysort[jx[k] & 0xffffu]) - x0);
            unsigned short d1 = f2b(b2f(ysort[jx[k] >> 16]) - x1);
            o[q] = (unsigned)d0 | ((unsigned)d1 << 16);
        }
        *(uint4*)(dfd + i * 4096 + t * 4) = make_uint4(o[0], o[1], o[2], o[3]);
    }
}

// ---------------------------------------------------------------------------
// Kernel 4: combine via bf16 MFMA, transpose fused into the LDS stage.
// Per block: stage diff[p][row0..row0+64] for p=0..99 (100 coalesced 128 B
// segments) pair-packed into Lp[k2][row] (dword = {k even lo16, k odd hi16});
// k2 rows 50..63 zeroed = NaN-safe K-pad.  A-frags: ds_read_b32 at (k2)*68+r
// dwords — 2-way bank aliasing = free (m136).  B = thbT in LDS [128][136].
// C[m=row][n=d]; out = x + C/P.  LDS 52,224 B -> 3 blocks/CU, 12 waves/CU.
// ---------------------------------------------------------------------------
__global__ __launch_bounds__(256) void k_comb(
    const float* __restrict__ x, const unsigned short* __restrict__ diff,
    const unsigned short* __restrict__ thbT, float* __restrict__ out) {
    __shared__ unsigned short ths[128 * 136]; // 34,816 B
    __shared__ unsigned Lp[64 * 68];          // 17,408 B  [k2][row] pair-packed
    const int tid  = threadIdx.x;
    const int w    = tid >> 6;                // wave -> rows w*16..+15
    const int lane = tid & 63;
    const int n16  = lane & 15;
    const int quad = lane >> 4;
    const int row0 = blockIdx.x * 64;

    for (int g = tid; g < 2048; g += 256) {   // thbT 128x128 bf16 -> LDS
        int r = g >> 4, c = (g & 15) << 3;
        *(uint4*)(ths + r * 136 + c) = *(const uint4*)(thbT + r * KPAD + c);
    }
    for (int g = tid; g < 952; g += 256) Lp[50 * 68 + g] = 0;   // k2=50..63 pad
    for (int g = tid; g < 400; g += 256) {    // 50 p-pairs x 8 row-groups
        int p2 = g >> 3, rg = (g & 7) << 3;
        uint4 a = *(const uint4*)(diff + (size_t)(2 * p2) * BN_ + row0 + rg);
        uint4 b = *(const uint4*)(diff + (size_t)(2 * p2 + 1) * BN_ + row0 + rg);
        unsigned* dst = Lp + p2 * 68 + rg;
        dst[0] = (a.x & 0xffffu) | (b.x << 16);
        dst[1] = (a.x >> 16)     | (b.x & 0xffff0000u);
        dst[2] = (a.y & 0xffffu) | (b.y << 16);
        dst[3] = (a.y >> 16)     | (b.y & 0xffff0000u);
        dst[4] = (a.z & 0xffffu) | (b.z << 16);
        dst[5] = (a.z >> 16)     | (b.z & 0xffff0000u);
        dst[6] = (a.w & 0xffffu) | (b.w << 16);
        dst[7] = (a.w >> 16)     | (b.w & 0xffff0000u);
    }
    __syncthreads();

    // A-frags: lane row r = w*16+n16, k = ks*32 + quad*8 + 0..7
    const int r = w * 16 + n16;
    short8 af[4];
    #pragma unroll
    for (int ks = 0; ks < 4; ++ks) {
        union { unsigned u[4]; short8 v; } tu;
        #pragma unroll
        for (int m = 0; m < 4; ++m)
            tu.u[m] = Lp[(ks * 16 + quad * 4 + m) * 68 + r];
        af[ks] = tu.v;
    }

    floatx4 acc[8];
    #pragma unroll
    for (int nt = 0; nt < 8; ++nt) {
        acc[nt] = (floatx4){0.f, 0.f, 0.f, 0.f};
        #pragma unroll
        for (int ks = 0; ks < 4; ++ks) {
            short8 b = *(const short8*)(ths + (nt * 16 + n16) * 136 + ks * 32 + quad * 8);
            acc[nt] = __builtin_amdgcn_mfma_f32_16x16x32_bf16(af[ks], b, acc[nt], 0, 0, 0);
        }
    }

    const float invP = 1.0f / (float)P_;
    const size_t rbase = (size_t)(row0 + w * 16 + quad * 4) * D_ + n16;
    #pragma unroll
    for (int nt = 0; nt < 8; ++nt)
        #pragma unroll
        for (int reg = 0; reg < 4; ++reg) {
            size_t o = rbase + (size_t)reg * D_ + nt * 16;
            out[o] = fmaf(acc[nt][reg], invP, x[o]);
        }
}

// ---------------------------------------------------------------------------
// Workspace (bytes): thb[0, 32KB) thbT[32KB, 64KB) xp[64KB, +13.1MB)
// yp(+13.1MB) => ~26.3 MB. diff overwrites xp in place.
// ---------------------------------------------------------------------------
extern "C" void kernel_launch(void* const* d_in, const int* in_sizes, int n_in,
                              void* d_out, int out_size, void* d_ws, size_t ws_size,
                              hipStream_t stream) {
    const float* x  = (const float*)d_in[0];
    const float* y  = (const float*)d_in[1];
    const float* th = (const float*)d_in[2];
    float* out = (float*)d_out;
    char*  wsb = (char*)d_ws;

    unsigned short* thb  = (unsigned short*)wsb;
    unsigned short* thbT = (unsigned short*)(wsb + 32768);
    unsigned short* xpb  = (unsigned short*)(wsb + 65536);
    unsigned short* ypb  = xpb + PBN_;

    k_norm<<<128, 128, 0, stream>>>(th, thb, thbT);
    k_proj<<<BN_ / 64, 256, 0, stream>>>(x, y, thb, xpb, ypb);
    k_sortdiff<<<P_ * B_, 1024, 0, stream>>>(xpb, ypb, xpb);
    k_comb<<<BN_ / 64, 256, 0, stream>>>(x, xpb, thbT, out);
}